// Round 2
// baseline (195.110 us; speedup 1.0000x reference)
//
#include <hip/hip_runtime.h>

#define NG 64
#define NT 8192
#define NE 64
#define Z_COEF 0.001f
#define A_COEF 0.001f

#define BLK 512
#define ITERS 8
#define TPB 512                  // tokens per block: 8 waves * 8 tokens * 8 iters
#define NBLK (NG * (NT / TPB))   // 1024

// ws: float probsum[NG*NE] | uint cnt[NG*NE] | float zsum[NG] | uint done

__global__ __launch_bounds__(BLK) void router_fused(
    const float* __restrict__ logits,
    const int* __restrict__ capp,
    float* __restrict__ probsum,
    unsigned int* __restrict__ cnt,
    float* __restrict__ zsum,
    unsigned int* __restrict__ done,
    float* __restrict__ out)
{
    const int tid  = threadIdx.x;
    const int lane = tid & 63;
    const int wv   = tid >> 6;      // wave in block 0..7
    const int c    = lane & 7;      // expert chunk (experts c*8..c*8+7)
    const int tk   = lane >> 3;     // token slot in wave

    const int g     = blockIdx.x >> 4;                 // 16 blocks per group
    const int tbase = (blockIdx.x & 15) * TPB + wv * 64;

    const float* row0 = logits + ((size_t)g * NT + tbase + tk) * NE + (c << 3);

    __shared__ float        s_ps[NE];
    __shared__ unsigned int s_cnt[NE];
    __shared__ float        s_z;
    __shared__ int          s_last;
    __shared__ float        s_aux[BLK / 64];

    if (tid < NE) { s_ps[tid] = 0.f; s_cnt[tid] = 0u; }
    if (tid == 0) s_z = 0.f;
    __syncthreads();

    float accp[8] = {0.f,0.f,0.f,0.f,0.f,0.f,0.f,0.f};
    float accz = 0.f;

    // prefetch iteration 0
    float4 va = *reinterpret_cast<const float4*>(row0);
    float4 vb = *reinterpret_cast<const float4*>(row0 + 4);

    for (int it = 0; it < ITERS; ++it) {
        // issue next iteration's loads before touching this iteration's data
        const int nit = (it + 1 < ITERS) ? (it + 1) : it;
        const float* nrow = row0 + (size_t)nit * (8 * NE);
        const float4 na = *reinterpret_cast<const float4*>(nrow);
        const float4 nb = *reinterpret_cast<const float4*>(nrow + 4);

        float v[8] = {va.x, va.y, va.z, va.w, vb.x, vb.y, vb.z, vb.w};

        // local max + argmax (strict > keeps lowest index on ties)
        float m = v[0]; int mi = 0;
#pragma unroll
        for (int j = 1; j < 8; ++j) {
            if (v[j] > m) { m = v[j]; mi = j; }
        }
        int me = (c << 3) + mi;
        const float ml = m;

        // exps against LOCAL max + local sum — independent of the max butterfly,
        // so the trans-pipe work overlaps the DS shuffles below
        float e[8]; float s = 0.f;
#pragma unroll
        for (int j = 0; j < 8; ++j) { e[j] = __expf(v[j] - ml); s += e[j]; }

        // butterfly group max/argmax across the token's 8 lanes
#pragma unroll
        for (int off = 1; off <= 4; off <<= 1) {
            const float om = __shfl_xor(m, off);
            const int  ome = __shfl_xor(me, off);
            if (om > m || (om == m && ome < me)) me = ome;
            m = fmaxf(m, om);
        }

        // rescale local sum to group max, butterfly-sum
        const float r = __expf(ml - m);
        s *= r;
#pragma unroll
        for (int off = 1; off <= 4; off <<= 1) s += __shfl_xor(s, off);

        const float wsc = r * __builtin_amdgcn_rcpf(s);
#pragma unroll
        for (int j = 0; j < 8; ++j) accp[j] += e[j] * wsc;

        if (c == 0) {
            const float lz = m + __logf(s);
            accz += lz * lz;
            atomicAdd(&s_cnt[me], 1u);
        }

        va = na; vb = nb;
    }

    // block-level reduce
#pragma unroll
    for (int j = 0; j < 8; ++j) atomicAdd(&s_ps[(c << 3) + j], accp[j]);
    if (c == 0) atomicAdd(&s_z, accz);
    __syncthreads();

    if (tid < NE) {
        atomicAdd(&probsum[g * NE + tid], s_ps[tid]);
        atomicAdd(&cnt[g * NE + tid], s_cnt[tid]);
    }
    if (tid == 0) atomicAdd(&zsum[g], s_z);

    // ---- last-block finalize ----
    __threadfence();
    if (tid == 0) {
        const unsigned int old = atomicAdd(done, 1u);
        s_last = (old == (unsigned int)(NBLK - 1));
    }
    __syncthreads();
    if (!s_last) return;
    __threadfence();

    const unsigned int C = (unsigned int)(*capp);

    float acc = 0.f;
    for (int gg = wv; gg < NG; gg += BLK / 64) {
        const unsigned int n = __hip_atomic_load(&cnt[gg * NE + lane],
                                                 __ATOMIC_RELAXED, __HIP_MEMORY_SCOPE_AGENT);
        const float P = __hip_atomic_load(&probsum[gg * NE + lane],
                                          __ATOMIC_RELAXED, __HIP_MEMORY_SCOPE_AGENT);
        float ovf = (n > C) ? (float)(n - C) : 0.f;
#pragma unroll
        for (int off = 1; off <= 32; off <<= 1) ovf += __shfl_xor(ovf, off);
        float ce = fminf((float)n, (float)C);
        if (lane == 0) ce += ovf;          // dropped tokens argmax to expert 0
        acc += ce * P;
    }
#pragma unroll
    for (int off = 1; off <= 32; off <<= 1) acc += __shfl_xor(acc, off);
    if (lane == 0) s_aux[wv] = acc;

    if (wv == 0) {
        float zz = __hip_atomic_load(&zsum[lane], __ATOMIC_RELAXED, __HIP_MEMORY_SCOPE_AGENT);
#pragma unroll
        for (int off = 1; off <= 32; off <<= 1) zz += __shfl_xor(zz, off);
        if (lane == 0) s_z = zz;
    }
    __syncthreads();

    if (tid == 0) {
        float A = 0.f;
#pragma unroll
        for (int i = 0; i < BLK / 64; ++i) A += s_aux[i];
        const float aux_loss = A * ((float)NE / ((float)NG * (float)NT * (float)NT));
        const float z_loss   = s_z / ((float)NG * (float)NT);
        out[0] = Z_COEF * z_loss + A_COEF * aux_loss;
    }
}

extern "C" void kernel_launch(void* const* d_in, const int* in_sizes, int n_in,
                              void* d_out, int out_size, void* d_ws, size_t ws_size,
                              hipStream_t stream)
{
    const float* logits = (const float*)d_in[0];
    // d_in[1] = attention_mask (unused by the reference forward)
    const int* cap = (const int*)d_in[2];

    float*        probsum = (float*)d_ws;
    unsigned int* cntp    = (unsigned int*)((char*)d_ws + (size_t)NG * NE * 4);
    float*        zsum    = (float*)((char*)d_ws + 2ull * NG * NE * 4);
    unsigned int* donep   = (unsigned int*)((char*)d_ws + 2ull * NG * NE * 4 + NG * 4);

    hipMemsetAsync(d_ws, 0, 2ull * NG * NE * 4 + NG * 4 + 4, stream);

    router_fused<<<NBLK, BLK, 0, stream>>>(logits, cap, probsum, cntp, zsum, donep,
                                           (float*)d_out);
}

// Round 3
// 65.685 us; speedup vs baseline: 2.9704x; 2.9704x over previous
//
#include <hip/hip_runtime.h>

#define NG 64
#define NT 8192
#define NE 64
#define Z_COEF 0.001f
#define A_COEF 0.001f

#define BLK 256
#define ITERS 4
#define TPB 256                  // tokens per block: 4 waves * 16 tokens * 4 iters
#define NBLK (NG * (NT / TPB))   // 2048

#define DPP_XOR1 0xB1            // quad_perm(1,0,3,2)
#define DPP_XOR2 0x4E            // quad_perm(2,3,0,1)

template <int CTRL>
__device__ __forceinline__ float fdpp(float x) {
    return __int_as_float(__builtin_amdgcn_mov_dpp(__float_as_int(x), CTRL, 0xF, 0xF, true));
}
template <int CTRL>
__device__ __forceinline__ int idpp(int x) {
    return __builtin_amdgcn_mov_dpp(x, CTRL, 0xF, 0xF, true);
}

// ws layout: float probsum[NG*NE] | uint cnt[NG*NE] | float zsum[NG]

__global__ __launch_bounds__(BLK) void router_main(
    const float* __restrict__ logits,
    float* __restrict__ probsum,
    unsigned int* __restrict__ cnt,
    float* __restrict__ zsum)
{
    const int tid  = threadIdx.x;
    const int lane = tid & 63;
    const int wv   = tid >> 6;      // wave in block (0..3)
    const int c    = lane & 3;      // expert chunk: experts c*16 .. c*16+15
    const int tk   = lane >> 2;     // token slot within the wave's 16

    const int g     = blockIdx.x >> 5;                    // 32 blocks per group
    const int tbase = (blockIdx.x & 31) * TPB + wv * (16 * ITERS);

    const float* row0 = logits + ((size_t)g * NT + tbase + tk) * NE + (c << 4);

    __shared__ float        s_ps[NE];
    __shared__ unsigned int s_cnt[NE];
    __shared__ float        s_z;
    if (tid < NE) { s_ps[tid] = 0.f; s_cnt[tid] = 0u; }
    if (tid == 0) s_z = 0.f;
    __syncthreads();

    float accp[16];
#pragma unroll
    for (int j = 0; j < 16; ++j) accp[j] = 0.f;
    float accz = 0.f;

    // prefetch iteration 0 (16 tokens * 64 floats = 1024 floats per iter stride)
    float4 a0 = *reinterpret_cast<const float4*>(row0);
    float4 a1 = *reinterpret_cast<const float4*>(row0 + 4);
    float4 a2 = *reinterpret_cast<const float4*>(row0 + 8);
    float4 a3 = *reinterpret_cast<const float4*>(row0 + 12);

    for (int it = 0; it < ITERS; ++it) {
        const int nit = (it + 1 < ITERS) ? (it + 1) : it;
        const float* nrow = row0 + (size_t)nit * (16 * NE);
        const float4 b0 = *reinterpret_cast<const float4*>(nrow);
        const float4 b1 = *reinterpret_cast<const float4*>(nrow + 4);
        const float4 b2 = *reinterpret_cast<const float4*>(nrow + 8);
        const float4 b3 = *reinterpret_cast<const float4*>(nrow + 12);

        float v[16] = {a0.x,a0.y,a0.z,a0.w, a1.x,a1.y,a1.z,a1.w,
                       a2.x,a2.y,a2.z,a2.w, a3.x,a3.y,a3.z,a3.w};

        // local max + argmax over 16 experts (strict > keeps lowest idx on ties)
        float m = v[0]; int mi = 0;
#pragma unroll
        for (int j = 1; j < 16; ++j) {
            if (v[j] > m) { m = v[j]; mi = j; }
        }
        int me = (c << 4) + mi;
        const float ml = m;

        // exps against LOCAL max + local sum (trans-pipe work, no cross-lane dep)
        float s = 0.f;
#pragma unroll
        for (int j = 0; j < 16; ++j) { v[j] = __expf(v[j] - ml); s += v[j]; }

        // cross-lane max/argmax over the token's 4 lanes — pure VALU via DPP
        {
            float om = fdpp<DPP_XOR1>(m);
            int  ome = idpp<DPP_XOR1>(me);
            bool u = (om > m) || (om == m && ome < me);
            me = u ? ome : me;
            m  = fmaxf(m, om);
            om  = fdpp<DPP_XOR2>(m);
            ome = idpp<DPP_XOR2>(me);
            u = (om > m) || (om == m && ome < me);
            me = u ? ome : me;
            m  = fmaxf(m, om);
        }

        // rescale local sum to group max, DPP butterfly-sum
        const float r = __expf(ml - m);
        s *= r;
        s += fdpp<DPP_XOR1>(s);
        s += fdpp<DPP_XOR2>(s);

        const float wsc = r * __builtin_amdgcn_rcpf(s);
#pragma unroll
        for (int j = 0; j < 16; ++j) accp[j] += v[j] * wsc;

        if (c == 0) {
            const float lz = m + __logf(s);
            accz += lz * lz;
            atomicAdd(&s_cnt[me], 1u);
        }

        a0 = b0; a1 = b1; a2 = b2; a3 = b3;
    }

    // block-level reduce in LDS
#pragma unroll
    for (int j = 0; j < 16; ++j) atomicAdd(&s_ps[(c << 4) + j], accp[j]);
    if (c == 0) atomicAdd(&s_z, accz);
    __syncthreads();

    if (tid < NE) {
        atomicAdd(&probsum[g * NE + tid], s_ps[tid]);
        atomicAdd(&cnt[g * NE + tid], s_cnt[tid]);
    }
    if (tid == 0) atomicAdd(&zsum[g], s_z);
}

__global__ __launch_bounds__(1024) void router_final(
    const float* __restrict__ probsum,
    const unsigned int* __restrict__ cnt,
    const float* __restrict__ zsum,
    const int* __restrict__ capp,
    float* __restrict__ out)
{
    const int tid  = threadIdx.x;
    const int lane = tid & 63;
    const int w    = tid >> 6;  // 0..15
    const unsigned int C = (unsigned int)(*capp);

    __shared__ float s_aux[16];
    __shared__ float s_zz;

    float acc = 0.f;
    for (int g = w; g < NG; g += 16) {
        const unsigned int n = cnt[g * NE + lane];
        const float        P = probsum[g * NE + lane];

        float ovf = (n > C) ? (float)(n - C) : 0.f;
#pragma unroll
        for (int off = 1; off <= 32; off <<= 1) ovf += __shfl_xor(ovf, off);

        float ce = fminf((float)n, (float)C);
        if (lane == 0) ce += ovf;   // dropped tokens all land on expert 0
        acc += ce * P;
    }
#pragma unroll
    for (int off = 1; off <= 32; off <<= 1) acc += __shfl_xor(acc, off);
    if (lane == 0) s_aux[w] = acc;

    if (w == 0) {
        float zz = zsum[lane];
#pragma unroll
        for (int off = 1; off <= 32; off <<= 1) zz += __shfl_xor(zz, off);
        if (lane == 0) s_zz = zz;
    }
    __syncthreads();

    if (tid == 0) {
        float A = 0.f;
#pragma unroll
        for (int i = 0; i < 16; ++i) A += s_aux[i];
        // aux = sum(c_e * P_e) * NE / (NG * NT * NT)
        const float aux_loss = A * ((float)NE / ((float)NG * (float)NT * (float)NT));
        const float z_loss   = s_zz / ((float)NG * (float)NT);
        out[0] = Z_COEF * z_loss + A_COEF * aux_loss;
    }
}

extern "C" void kernel_launch(void* const* d_in, const int* in_sizes, int n_in,
                              void* d_out, int out_size, void* d_ws, size_t ws_size,
                              hipStream_t stream)
{
    const float* logits = (const float*)d_in[0];
    // d_in[1] = attention_mask (unused by the reference forward)
    const int* cap = (const int*)d_in[2];

    float*        probsum = (float*)d_ws;
    unsigned int* cntp    = (unsigned int*)((char*)d_ws + (size_t)NG * NE * 4);
    float*        zsum    = (float*)((char*)d_ws + 2ull * NG * NE * 4);

    hipMemsetAsync(d_ws, 0, 2ull * NG * NE * 4 + NG * 4, stream);

    router_main<<<NBLK, BLK, 0, stream>>>(logits, probsum, cntp, zsum);
    router_final<<<1, 1024, 0, stream>>>(probsum, cntp, zsum, cap, (float*)d_out);
}

// Round 4
// 40.029 us; speedup vs baseline: 4.8742x; 1.6409x over previous
//
#include <hip/hip_runtime.h>

#define NG 64
#define NT 8192
#define NE 64
#define Z_COEF 0.001f
#define A_COEF 0.001f

#define BLK 512                  // 8 waves
#define ITERS 4                  // 16 tokens per iter per wave
#define TPW 64                   // tokens per wave
#define TPB 512                  // tokens per block (8 waves * 64)
#define NBLK (NG * (NT / TPB))   // 1024

#define DPP_XOR1  0xB1           // quad_perm(1,0,3,2)  : lane ^ 1
#define DPP_XOR2  0x4E           // quad_perm(2,3,0,1)  : lane ^ 2
#define DPP_HMIRR 0x141          // row_half_mirror     : lane ^ 7 within 8
#define DPP_MIRR  0x140          // row_mirror          : lane ^ 15 within 16

template <int CTRL>
__device__ __forceinline__ float fdpp(float x) {
    return __int_as_float(__builtin_amdgcn_mov_dpp(__float_as_int(x), CTRL, 0xF, 0xF, true));
}
template <int CTRL>
__device__ __forceinline__ int idpp(int x) {
    return __builtin_amdgcn_mov_dpp(x, CTRL, 0xF, 0xF, true);
}

// one butterfly stage for (max, argmax); complement-coset pairing per stage
template <int CTRL>
__device__ __forceinline__ void bfly_maxidx(float& m, int& me) {
    const float om  = fdpp<CTRL>(m);
    const int   ome = idpp<CTRL>(me);
    const bool  u   = (om > m) || (om == m && ome < me);
    me = u ? ome : me;
    m  = fmaxf(m, om);
}

// ws layout: float probsum[NG*NE] | uint cnt[NG*NE] | float zsum[NG]

__global__ __launch_bounds__(BLK) void router_main(
    const float* __restrict__ logits,
    float* __restrict__ probsum,
    unsigned int* __restrict__ cnt,
    float* __restrict__ zsum)
{
    const int tid  = threadIdx.x;
    const int lane = tid & 63;
    const int wv   = tid >> 6;       // wave in block 0..7
    const int c    = lane & 15;      // expert chunk: experts 4c .. 4c+3

    const int g     = blockIdx.x >> 4;                  // 16 blocks per group
    const int tbase = (blockIdx.x & 15) * TPB + wv * TPW;

    // fully coalesced: per instruction k, lane l reads bytes [k*1024 + l*16)
    // of the wave's 4KB token chunk -> token 4k+(l>>4), experts [4*(l&15),+4)
    const float* p0 = logits + ((size_t)g * NT + tbase) * NE + lane * 4;

    __shared__ float        s_ps[NE];
    __shared__ unsigned int s_cnt[NE];
    __shared__ float        s_z;
    if (tid < NE) { s_ps[tid] = 0.f; s_cnt[tid] = 0u; }
    if (tid == 0) s_z = 0.f;
    __syncthreads();

    float accp[4] = {0.f, 0.f, 0.f, 0.f};
    float accz = 0.f;

    float4 cur[4], nxt[4];
#pragma unroll
    for (int k = 0; k < 4; ++k)
        cur[k] = *reinterpret_cast<const float4*>(p0 + k * 256);

    for (int it = 0; it < ITERS; ++it) {
        const int nit = (it + 1 < ITERS) ? (it + 1) : it;
        const float* pn = p0 + (size_t)nit * 1024;
#pragma unroll
        for (int k = 0; k < 4; ++k)
            nxt[k] = *reinterpret_cast<const float4*>(pn + k * 256);

#pragma unroll
        for (int k = 0; k < 4; ++k) {
            const float v0 = cur[k].x, v1 = cur[k].y, v2 = cur[k].z, v3 = cur[k].w;

            // local max + argmax over this lane's 4 experts (first idx on ties)
            float m = v0; int mi = 0;
            if (v1 > m) { m = v1; mi = 1; }
            if (v2 > m) { m = v2; mi = 2; }
            if (v3 > m) { m = v3; mi = 3; }
            int me = (c << 2) + mi;
            const float ml = m;

            // exps against LOCAL max (overlaps with the butterfly below)
            const float e0 = __expf(v0 - ml), e1 = __expf(v1 - ml);
            const float e2 = __expf(v2 - ml), e3 = __expf(v3 - ml);
            float s = (e0 + e1) + (e2 + e3);

            // 16-lane max/argmax butterfly, pure-VALU DPP
            bfly_maxidx<DPP_XOR1>(m, me);
            bfly_maxidx<DPP_XOR2>(m, me);
            bfly_maxidx<DPP_HMIRR>(m, me);
            bfly_maxidx<DPP_MIRR>(m, me);

            // rescale local sum to group max, 16-lane sum butterfly
            const float r = __expf(ml - m);
            s *= r;
            s += fdpp<DPP_XOR1>(s);
            s += fdpp<DPP_XOR2>(s);
            s += fdpp<DPP_HMIRR>(s);
            s += fdpp<DPP_MIRR>(s);

            const float wsc = r * __builtin_amdgcn_rcpf(s);
            accp[0] += e0 * wsc;
            accp[1] += e1 * wsc;
            accp[2] += e2 * wsc;
            accp[3] += e3 * wsc;

            if (c == 0) {                       // lanes 0,16,32,48: one token each
                const float lz = m + __logf(s);
                accz += lz * lz;
                atomicAdd(&s_cnt[me], 1u);
            }
        }
#pragma unroll
        for (int k = 0; k < 4; ++k) cur[k] = nxt[k];
    }

    // fold the 4 token-subgroups (lanes l, l^16, l^32 share an expert chunk)
#pragma unroll
    for (int j = 0; j < 4; ++j) {
        accp[j] += __shfl_xor(accp[j], 16);
        accp[j] += __shfl_xor(accp[j], 32);
    }
    if (lane < 16) {
#pragma unroll
        for (int j = 0; j < 4; ++j) atomicAdd(&s_ps[(c << 2) + j], accp[j]);
    }
    if (c == 0) atomicAdd(&s_z, accz);
    __syncthreads();

    if (tid < NE) {
        atomicAdd(&probsum[g * NE + tid], s_ps[tid]);
        atomicAdd(&cnt[g * NE + tid], s_cnt[tid]);
    }
    if (tid == 0) atomicAdd(&zsum[g], s_z);
}

__global__ __launch_bounds__(1024) void router_final(
    const float* __restrict__ probsum,
    const unsigned int* __restrict__ cnt,
    const float* __restrict__ zsum,
    const int* __restrict__ capp,
    float* __restrict__ out)
{
    const int tid  = threadIdx.x;
    const int lane = tid & 63;
    const int w    = tid >> 6;  // 0..15
    const unsigned int C = (unsigned int)(*capp);

    __shared__ float s_aux[16];
    __shared__ float s_zz;

    float acc = 0.f;
    for (int g = w; g < NG; g += 16) {
        const unsigned int n = cnt[g * NE + lane];
        const float        P = probsum[g * NE + lane];

        float ovf = (n > C) ? (float)(n - C) : 0.f;
#pragma unroll
        for (int off = 1; off <= 32; off <<= 1) ovf += __shfl_xor(ovf, off);

        float ce = fminf((float)n, (float)C);
        if (lane == 0) ce += ovf;   // dropped tokens all land on expert 0
        acc += ce * P;
    }
#pragma unroll
    for (int off = 1; off <= 32; off <<= 1) acc += __shfl_xor(acc, off);
    if (lane == 0) s_aux[w] = acc;

    if (w == 0) {
        float zz = zsum[lane];
#pragma unroll
        for (int off = 1; off <= 32; off <<= 1) zz += __shfl_xor(zz, off);
        if (lane == 0) s_zz = zz;
    }
    __syncthreads();

    if (tid == 0) {
        float A = 0.f;
#pragma unroll
        for (int i = 0; i < 16; ++i) A += s_aux[i];
        // aux = sum(c_e * P_e) * NE / (NG * NT * NT)
        const float aux_loss = A * ((float)NE / ((float)NG * (float)NT * (float)NT));
        const float z_loss   = s_zz / ((float)NG * (float)NT);
        out[0] = Z_COEF * z_loss + A_COEF * aux_loss;
    }
}

extern "C" void kernel_launch(void* const* d_in, const int* in_sizes, int n_in,
                              void* d_out, int out_size, void* d_ws, size_t ws_size,
                              hipStream_t stream)
{
    const float* logits = (const float*)d_in[0];
    // d_in[1] = attention_mask (unused by the reference forward)
    const int* cap = (const int*)d_in[2];

    float*        probsum = (float*)d_ws;
    unsigned int* cntp    = (unsigned int*)((char*)d_ws + (size_t)NG * NE * 4);
    float*        zsum    = (float*)((char*)d_ws + 2ull * NG * NE * 4);

    hipMemsetAsync(d_ws, 0, 2ull * NG * NE * 4 + NG * 4, stream);

    router_main<<<NBLK, BLK, 0, stream>>>(logits, probsum, cntp, zsum);
    router_final<<<1, 1024, 0, stream>>>(probsum, cntp, zsum, cap, (float*)d_out);
}

// Round 5
// 37.123 us; speedup vs baseline: 5.2557x; 1.0783x over previous
//
#include <hip/hip_runtime.h>

#define NG 64
#define NT 8192
#define NE 64
#define Z_COEF 0.001f
#define A_COEF 0.001f

#define BLK 512                  // 8 waves
#define ITERS 4                  // 16 tokens per iter per wave
#define TPW 64                   // tokens per wave
#define TPB 512                  // tokens per block (8 waves * 64)
#define NBLK (NG * (NT / TPB))   // 1024 (16 blocks per group)

#define DPP_XOR1  0xB1           // quad_perm(1,0,3,2)  : lane ^ 1
#define DPP_XOR2  0x4E           // quad_perm(2,3,0,1)  : lane ^ 2
#define DPP_HMIRR 0x141          // row_half_mirror     : lane ^ 7 within 8
#define DPP_MIRR  0x140          // row_mirror          : lane ^ 15 within 16

template <int CTRL>
__device__ __forceinline__ float fdpp(float x) {
    return __int_as_float(__builtin_amdgcn_mov_dpp(__float_as_int(x), CTRL, 0xF, 0xF, true));
}
template <int CTRL>
__device__ __forceinline__ int idpp(int x) {
    return __builtin_amdgcn_mov_dpp(x, CTRL, 0xF, 0xF, true);
}

template <int CTRL>
__device__ __forceinline__ void bfly_maxidx(float& m, int& me) {
    const float om  = fdpp<CTRL>(m);
    const int   ome = idpp<CTRL>(me);
    const bool  u   = (om > m) || (om == m && ome < me);
    me = u ? ome : me;
    m  = fmaxf(m, om);
}

// ws layout (all written every launch, no zeroing needed):
//   float pps [NBLK][NE]   per-block prob sums
//   uint  pcnt[NBLK][NE]   per-block argmax counts
//   float pz  [NBLK]       per-block z partials

__global__ __launch_bounds__(BLK) void router_main(
    const float* __restrict__ logits,
    float* __restrict__ pps,
    unsigned int* __restrict__ pcnt,
    float* __restrict__ pz)
{
    const int tid  = threadIdx.x;
    const int lane = tid & 63;
    const int wv   = tid >> 6;       // wave in block 0..7
    const int c    = lane & 15;      // expert chunk: experts 4c .. 4c+3

    const int g     = blockIdx.x >> 4;                  // 16 blocks per group
    const int tbase = (blockIdx.x & 15) * TPB + wv * TPW;

    // fully coalesced: per instruction k, lane l reads bytes [k*1024 + l*16)
    // of the wave's 4KB token chunk -> token 4k+(l>>4), experts [4*(l&15),+4)
    const float* p0 = logits + ((size_t)g * NT + tbase) * NE + lane * 4;

    __shared__ float        s_ps[NE];
    __shared__ unsigned int s_cnt[NE];
    __shared__ float        s_z;
    if (tid < NE) { s_ps[tid] = 0.f; s_cnt[tid] = 0u; }
    if (tid == 0) s_z = 0.f;
    __syncthreads();

    float accp[4] = {0.f, 0.f, 0.f, 0.f};
    float accz = 0.f;

    float4 cur[4], nxt[4];
#pragma unroll
    for (int k = 0; k < 4; ++k)
        cur[k] = *reinterpret_cast<const float4*>(p0 + k * 256);

    for (int it = 0; it < ITERS; ++it) {
        const int nit = (it + 1 < ITERS) ? (it + 1) : it;
        const float* pn = p0 + (size_t)nit * 1024;
#pragma unroll
        for (int k = 0; k < 4; ++k)
            nxt[k] = *reinterpret_cast<const float4*>(pn + k * 256);

#pragma unroll
        for (int k = 0; k < 4; ++k) {
            const float v0 = cur[k].x, v1 = cur[k].y, v2 = cur[k].z, v3 = cur[k].w;

            // local max + argmax over this lane's 4 experts (first idx on ties)
            float m = v0; int mi = 0;
            if (v1 > m) { m = v1; mi = 1; }
            if (v2 > m) { m = v2; mi = 2; }
            if (v3 > m) { m = v3; mi = 3; }
            int me = (c << 2) + mi;
            const float ml = m;

            // exps against LOCAL max (overlaps with the butterfly below)
            const float e0 = __expf(v0 - ml), e1 = __expf(v1 - ml);
            const float e2 = __expf(v2 - ml), e3 = __expf(v3 - ml);
            float s = (e0 + e1) + (e2 + e3);

            // 16-lane max/argmax butterfly, pure-VALU DPP
            bfly_maxidx<DPP_XOR1>(m, me);
            bfly_maxidx<DPP_XOR2>(m, me);
            bfly_maxidx<DPP_HMIRR>(m, me);
            bfly_maxidx<DPP_MIRR>(m, me);

            // rescale local sum to group max, 16-lane sum butterfly
            const float r = __expf(ml - m);
            s *= r;
            s += fdpp<DPP_XOR1>(s);
            s += fdpp<DPP_XOR2>(s);
            s += fdpp<DPP_HMIRR>(s);
            s += fdpp<DPP_MIRR>(s);

            const float wsc = r * __builtin_amdgcn_rcpf(s);
            accp[0] += e0 * wsc;
            accp[1] += e1 * wsc;
            accp[2] += e2 * wsc;
            accp[3] += e3 * wsc;

            if (c == 0) {                       // lanes 0,16,32,48: one token each
                const float lz = m + __logf(s);
                accz += lz * lz;
                atomicAdd(&s_cnt[me], 1u);
            }
        }
#pragma unroll
        for (int k = 0; k < 4; ++k) cur[k] = nxt[k];
    }

    // fold the 4 token-subgroups (lanes l, l^16, l^32 share an expert chunk)
#pragma unroll
    for (int j = 0; j < 4; ++j) {
        accp[j] += __shfl_xor(accp[j], 16);
        accp[j] += __shfl_xor(accp[j], 32);
    }
    if (lane < 16) {
#pragma unroll
        for (int j = 0; j < 4; ++j) atomicAdd(&s_ps[(c << 2) + j], accp[j]);
    }
    if (c == 0) atomicAdd(&s_z, accz);
    __syncthreads();

    // per-block partials: plain stores, every slot owned by exactly one block
    const int row = blockIdx.x;
    if (tid < NE) {
        pps [row * NE + tid] = s_ps[tid];
        pcnt[row * NE + tid] = s_cnt[tid];
    }
    if (tid == 0) pz[row] = s_z;
}

__global__ __launch_bounds__(1024) void router_final(
    const float* __restrict__ pps,
    const unsigned int* __restrict__ pcnt,
    const float* __restrict__ pz,
    const int* __restrict__ capp,
    float* __restrict__ out)
{
    const int tid  = threadIdx.x;
    const int lane = tid & 63;   // expert
    const int w    = tid >> 6;   // wave 0..15
    const unsigned int C = (unsigned int)(*capp);

    __shared__ float s_aux[16];
    __shared__ float s_zz[16];

    float acc = 0.f;
#pragma unroll
    for (int gi = 0; gi < NG / 16; ++gi) {
        const int g = w + gi * 16;
        unsigned int n = 0u;
        float        P = 0.f;
#pragma unroll
        for (int b = 0; b < 16; ++b) {
            const int row = g * 16 + b;          // coalesced: lane = expert
            n += pcnt[row * NE + lane];
            P += pps [row * NE + lane];
        }
        float ovf = (n > C) ? (float)(n - C) : 0.f;
#pragma unroll
        for (int off = 1; off <= 32; off <<= 1) ovf += __shfl_xor(ovf, off);
        float ce = fminf((float)n, (float)C);
        if (lane == 0) ce += ovf;    // dropped tokens argmax to expert 0
        acc += ce * P;
    }
#pragma unroll
    for (int off = 1; off <= 32; off <<= 1) acc += __shfl_xor(acc, off);
    if (lane == 0) s_aux[w] = acc;

    // z: 1024 partials, one per main-block
    float zz = pz[tid];
#pragma unroll
    for (int off = 1; off <= 32; off <<= 1) zz += __shfl_xor(zz, off);
    if (lane == 0) s_zz[w] = zz;
    __syncthreads();

    if (tid == 0) {
        float A = 0.f, Z = 0.f;
#pragma unroll
        for (int i = 0; i < 16; ++i) { A += s_aux[i]; Z += s_zz[i]; }
        // aux = sum_e c_e * P_e * NE / (NG * NT * NT)
        const float aux_loss = A * ((float)NE / ((float)NG * (float)NT * (float)NT));
        const float z_loss   = Z / ((float)NG * (float)NT);
        out[0] = Z_COEF * z_loss + A_COEF * aux_loss;
    }
}

extern "C" void kernel_launch(void* const* d_in, const int* in_sizes, int n_in,
                              void* d_out, int out_size, void* d_ws, size_t ws_size,
                              hipStream_t stream)
{
    const float* logits = (const float*)d_in[0];
    // d_in[1] = attention_mask (unused by the reference forward)
    const int* cap = (const int*)d_in[2];

    float*        pps  = (float*)d_ws;
    unsigned int* pcnt = (unsigned int*)((char*)d_ws + (size_t)NBLK * NE * 4);
    float*        pz   = (float*)((char*)d_ws + 2ull * NBLK * NE * 4);

    router_main<<<NBLK, BLK, 0, stream>>>(logits, pps, pcnt, pz);
    router_final<<<1, 1024, 0, stream>>>(pps, pcnt, pz, cap, (float*)d_out);
}